// Round 1
// 180.565 us; speedup vs baseline: 1.0364x; 1.0364x over previous
//
#include <hip/hip_runtime.h>

#define BATCH        16384
#define SEQ          500
#define NUM_BUCKETS  4000000
#define NUM_FIELDS   63
#define NUM_SEGMENTS 64
#define BLOCK        256
#define ROWS_PER_BLK 4          // one wave per batch row

typedef int         int4v   __attribute__((ext_vector_type(4)));
typedef float       float4v __attribute__((ext_vector_type(4)));
typedef signed char schar;
typedef schar       char4v  __attribute__((ext_vector_type(4)));

#define N_VEC4     (NUM_BUCKETS / 4)        // 1,000,000 float4 groups
#define SLICE_LOG2 12                       // 4096 floats per quant slice
#define N_SLICES   ((NUM_BUCKETS + 4095) >> SLICE_LOG2)   // 977
#define SCALES_OFF NUM_BUCKETS              // byte offset of scales[] in d_ws

// ---- k1: ONE-pass per-slice quantization.
// Each block owns one 4096-float slice: load -> block absmax -> quantize ->
// store int8 + the slice's dequant step. No global scale => no absmax
// pre-pass, no init kernel, no grid sync. fp32 table read ONCE (16 MB),
// normal (cacheable) loads so the table stays L3-resident across bench iters.
__global__ __launch_bounds__(BLOCK) void quant_slice(
    const float4v* __restrict__ src, char4v* __restrict__ dst,
    float* __restrict__ scales)
{
    __shared__ float red[BLOCK / 64];
    const int t     = threadIdx.x;
    const int base4 = blockIdx.x << (SLICE_LOG2 - 2);   // float4 index of slice start

    float4v v[4];
    float m = 0.0f;
    #pragma unroll
    for (int k = 0; k < 4; ++k) {
        const int i4 = base4 + k * BLOCK + t;
        if (i4 < N_VEC4) {
            v[k] = src[i4];
            #pragma unroll
            for (int j = 0; j < 4; ++j) m = fmaxf(m, fabsf(v[k][j]));
        } else {
            v[k] = (float4v){0.f, 0.f, 0.f, 0.f};
        }
    }
    // wave max
    #pragma unroll
    for (int off = 32; off >= 1; off >>= 1)
        m = fmaxf(m, __shfl_down(m, off, 64));
    if ((t & 63) == 0) red[t >> 6] = m;
    __syncthreads();
    const float bm  = fmaxf(fmaxf(red[0], red[1]), fmaxf(red[2], red[3]));
    const float inv = (bm > 0.f) ? 127.0f / bm : 0.0f;
    if (t == 0) scales[blockIdx.x] = bm * (1.0f / 127.0f);   // dequant step

    #pragma unroll
    for (int k = 0; k < 4; ++k) {
        const int i4 = base4 + k * BLOCK + t;
        if (i4 < N_VEC4) {
            char4v q;
            #pragma unroll
            for (int j = 0; j < 4; ++j) {
                float r = fminf(fmaxf(v[k][j] * inv, -127.f), 127.f);
                q[j] = (schar)(int)rintf(r);
            }
            dst[i4] = q;
        }
    }
}

// ---- k2: main — int8 table gather (4 MB, L2-resident) + LDS segment-sum.
// Dequant is per-element via scales[bucket>>12]: a 3.9 KB table, L1-resident,
// so it adds no L2 gather traffic (the suspected bottleneck pipe).
__global__ __launch_bounds__(BLOCK, 8) void wide_pool_i8(
    const int*   __restrict__ indexes,
    const int*   __restrict__ fields,
    const float* __restrict__ values,
    const schar* __restrict__ table8,
    const float* __restrict__ scales,
    float*       __restrict__ out)
{
    __shared__ float acc[ROWS_PER_BLK][NUM_SEGMENTS];

    const int tid  = threadIdx.x;
    const int wave = tid >> 6;
    const int lane = tid & 63;

    acc[wave][lane] = 0.0f;
    __syncthreads();

    const long row  = (long)blockIdx.x * ROWS_PER_BLK + wave;
    const long base = row * SEQ;

    const int4v*   idx4 = (const int4v*)  (indexes + base);
    const int4v*   fld4 = (const int4v*)  (fields  + base);
    const float4v* val4 = (const float4v*)(values  + base);

    const bool second = (lane < 125 - 64);   // 500 = 125 vec4 per row

    // stage 1: non-temporal stream loads (zero reuse -> keep L2 for the table)
    int4v   ia = __builtin_nontemporal_load(&idx4[lane]);
    int4v   fa = __builtin_nontemporal_load(&fld4[lane]);
    float4v va = __builtin_nontemporal_load(&val4[lane]);
    int4v   ib = {0, 0, 0, 0};
    int4v   fb = {0, 0, 0, 0};
    float4v vb = {0.f, 0.f, 0.f, 0.f};
    if (second) {
        ib = __builtin_nontemporal_load(&idx4[lane + 64]);
        fb = __builtin_nontemporal_load(&fld4[lane + 64]);
        vb = __builtin_nontemporal_load(&val4[lane + 64]);
    }

    // stage 2: 8 independent int8 gathers + 8 L1-hit scale gathers in flight
    // (bucket 0 quantizes to 0 -> no padding guard needed)
    float e[8];
    #pragma unroll
    for (int j = 0; j < 4; ++j) {
        const int b = ia[j] % NUM_BUCKETS;
        e[j] = (float)table8[b] * scales[b >> SLICE_LOG2];
    }
    #pragma unroll
    for (int j = 0; j < 4; ++j) {
        if (second) {
            const int b = ib[j] % NUM_BUCKETS;
            e[4 + j] = (float)table8[b] * scales[b >> SLICE_LOG2];
        } else {
            e[4 + j] = 0.0f;
        }
    }

    // stage 3: acc += dequant(q) * v  (already dequantized per element)
    #pragma unroll
    for (int j = 0; j < 4; ++j)
        atomicAdd(&acc[wave][fa[j] & (NUM_SEGMENTS - 1)], e[j] * va[j]);
    if (second) {
        #pragma unroll
        for (int j = 0; j < 4; ++j)
            atomicAdd(&acc[wave][fb[j] & (NUM_SEGMENTS - 1)], e[4 + j] * vb[j]);
    }

    __syncthreads();

    if (lane >= 1)
        __builtin_nontemporal_store(acc[wave][lane],
                                    &out[row * NUM_FIELDS + (lane - 1)]);
}

// ---- fallback: fp32 table direct (only if d_ws can't hold table + scales)
__global__ __launch_bounds__(BLOCK, 8) void wide_pool_f32(
    const int*   __restrict__ indexes,
    const int*   __restrict__ fields,
    const float* __restrict__ values,
    const float* __restrict__ table,
    float*       __restrict__ out)
{
    __shared__ float acc[ROWS_PER_BLK][NUM_SEGMENTS];
    const int tid  = threadIdx.x;
    const int wave = tid >> 6;
    const int lane = tid & 63;
    acc[wave][lane] = 0.0f;
    __syncthreads();
    const long row  = (long)blockIdx.x * ROWS_PER_BLK + wave;
    const long base = row * SEQ;
    const int4v*   idx4 = (const int4v*)  (indexes + base);
    const int4v*   fld4 = (const int4v*)  (fields  + base);
    const float4v* val4 = (const float4v*)(values  + base);
    const bool second = (lane < 125 - 64);
    int4v   ia = __builtin_nontemporal_load(&idx4[lane]);
    int4v   fa = __builtin_nontemporal_load(&fld4[lane]);
    float4v va = __builtin_nontemporal_load(&val4[lane]);
    int4v   ib = {0,0,0,0}; int4v fb = {0,0,0,0}; float4v vb = {0.f,0.f,0.f,0.f};
    if (second) {
        ib = __builtin_nontemporal_load(&idx4[lane + 64]);
        fb = __builtin_nontemporal_load(&fld4[lane + 64]);
        vb = __builtin_nontemporal_load(&val4[lane + 64]);
    }
    float e[8];
    #pragma unroll
    for (int j = 0; j < 4; ++j) e[j] = table[ia[j] % NUM_BUCKETS];
    #pragma unroll
    for (int j = 0; j < 4; ++j) e[4 + j] = second ? table[ib[j] % NUM_BUCKETS] : 0.0f;
    #pragma unroll
    for (int j = 0; j < 4; ++j)
        atomicAdd(&acc[wave][fa[j] & (NUM_SEGMENTS - 1)], e[j] * va[j]);
    if (second) {
        #pragma unroll
        for (int j = 0; j < 4; ++j)
            atomicAdd(&acc[wave][fb[j] & (NUM_SEGMENTS - 1)], e[4 + j] * vb[j]);
    }
    __syncthreads();
    if (lane >= 1) out[row * NUM_FIELDS + (lane - 1)] = acc[wave][lane];
}

extern "C" void kernel_launch(void* const* d_in, const int* in_sizes, int n_in,
                              void* d_out, int out_size, void* d_ws, size_t ws_size,
                              hipStream_t stream) {
    const int*   indexes = (const int*)  d_in[0];
    const int*   fields  = (const int*)  d_in[1];
    const float* values  = (const float*)d_in[2];
    const float* table   = (const float*)d_in[3];
    float*       out     = (float*)      d_out;

    const size_t need = (size_t)NUM_BUCKETS + 4 * (size_t)N_SLICES;  // 4 MB + 3.9 KB
    if (ws_size >= need) {
        schar* t8  = (schar*)d_ws;
        float* scl = (float*)((char*)d_ws + SCALES_OFF);
        quant_slice<<<N_SLICES, BLOCK, 0, stream>>>(
            (const float4v*)table, (char4v*)t8, scl);
        wide_pool_i8<<<BATCH / ROWS_PER_BLK, BLOCK, 0, stream>>>(
            indexes, fields, values, t8, scl, out);
    } else {
        wide_pool_f32<<<BATCH / ROWS_PER_BLK, BLOCK, 0, stream>>>(
            indexes, fields, values, table, out);
    }
}

// Round 2
// 175.964 us; speedup vs baseline: 1.0635x; 1.0261x over previous
//
#include <hip/hip_runtime.h>

#define BATCH        16384
#define SEQ          500
#define NUM_BUCKETS  4000000
#define NUM_FIELDS   63
#define NUM_SEGMENTS 64

typedef int         int4v   __attribute__((ext_vector_type(4)));
typedef float       float4v __attribute__((ext_vector_type(4)));
typedef signed char schar;
typedef schar       char4v  __attribute__((ext_vector_type(4)));

#define N_VEC4     (NUM_BUCKETS / 4)        // 1,000,000 float4 groups
#define SLICE_LOG2 12                       // 4096 floats per quant slice
#define N_SLICES   ((NUM_BUCKETS + 4095) >> SLICE_LOG2)   // 977
#define SCALES_OFF NUM_BUCKETS              // byte offset of scales[] in d_ws

// main-kernel geometry: 8 rows per block, one wave per row
#define BLOCK_MAIN   512
#define ROWS_PER_BLK 8

// quant-kernel geometry
#define BLOCK_Q 256

// ---- k1: ONE-pass per-slice quantization.
// Each block owns one 4096-float slice: load -> block absmax -> quantize ->
// store int8 + the slice's dequant step. fp32 table read ONCE (16 MB),
// cacheable loads so the table stays L3-resident across bench iters.
__global__ __launch_bounds__(BLOCK_Q) void quant_slice(
    const float4v* __restrict__ src, char4v* __restrict__ dst,
    float* __restrict__ scales)
{
    __shared__ float red[BLOCK_Q / 64];
    const int t     = threadIdx.x;
    const int base4 = blockIdx.x << (SLICE_LOG2 - 2);   // float4 index of slice start

    float4v v[4];
    float m = 0.0f;
    #pragma unroll
    for (int k = 0; k < 4; ++k) {
        const int i4 = base4 + k * BLOCK_Q + t;
        if (i4 < N_VEC4) {
            v[k] = src[i4];
            #pragma unroll
            for (int j = 0; j < 4; ++j) m = fmaxf(m, fabsf(v[k][j]));
        } else {
            v[k] = (float4v){0.f, 0.f, 0.f, 0.f};
        }
    }
    #pragma unroll
    for (int off = 32; off >= 1; off >>= 1)
        m = fmaxf(m, __shfl_down(m, off, 64));
    if ((t & 63) == 0) red[t >> 6] = m;
    __syncthreads();
    const float bm  = fmaxf(fmaxf(red[0], red[1]), fmaxf(red[2], red[3]));
    const float inv = (bm > 0.f) ? 127.0f / bm : 0.0f;
    if (t == 0) scales[blockIdx.x] = bm * (1.0f / 127.0f);   // dequant step

    #pragma unroll
    for (int k = 0; k < 4; ++k) {
        const int i4 = base4 + k * BLOCK_Q + t;
        if (i4 < N_VEC4) {
            char4v q;
            #pragma unroll
            for (int j = 0; j < 4; ++j) {
                float r = fminf(fmaxf(v[k][j] * inv, -127.f), 127.f);
                q[j] = (schar)(int)rintf(r);
            }
            dst[i4] = q;
        }
    }
}

// ---- k2: main — int8 table gather (4 MB, L2-resident) + LDS segment-sum.
// Per-slice dequant scales (3.9 KB) are staged in LDS once per block, so the
// only divergent VMEM traffic is the 8 int8 table gathers per thread — that
// request pipe is the kernel's bottleneck (1.26 TB/s HBM, 6% VALU, 0 bank
// conflicts => gather-rate bound). Random ds_read over 977 words ~ 2 lanes
// per bank ~ free (m136).
__global__ __launch_bounds__(BLOCK_MAIN, 8) void wide_pool_i8(
    const int*   __restrict__ indexes,
    const int*   __restrict__ fields,
    const float* __restrict__ values,
    const schar* __restrict__ table8,
    const float* __restrict__ scales,
    float*       __restrict__ out)
{
    __shared__ float acc[ROWS_PER_BLK][NUM_SEGMENTS];
    __shared__ float sscale[N_SLICES];

    const int tid  = threadIdx.x;
    const int wave = tid >> 6;
    const int lane = tid & 63;

    // acc init (512 threads cover 8x64 exactly) + scale stage, one barrier
    acc[wave][lane] = 0.0f;
    for (int i = tid; i < N_SLICES; i += BLOCK_MAIN)
        sscale[i] = scales[i];
    __syncthreads();

    const long row  = (long)blockIdx.x * ROWS_PER_BLK + wave;
    const long base = row * SEQ;

    const int4v*   idx4 = (const int4v*)  (indexes + base);
    const int4v*   fld4 = (const int4v*)  (fields  + base);
    const float4v* val4 = (const float4v*)(values  + base);

    const bool second = (lane < 125 - 64);   // 500 = 125 vec4 per row

    // stage 1: non-temporal stream loads (zero reuse -> keep L2 for the table)
    int4v   ia = __builtin_nontemporal_load(&idx4[lane]);
    int4v   fa = __builtin_nontemporal_load(&fld4[lane]);
    float4v va = __builtin_nontemporal_load(&val4[lane]);
    int4v   ib = {0, 0, 0, 0};
    int4v   fb = {0, 0, 0, 0};
    float4v vb = {0.f, 0.f, 0.f, 0.f};
    if (second) {
        ib = __builtin_nontemporal_load(&idx4[lane + 64]);
        fb = __builtin_nontemporal_load(&fld4[lane + 64]);
        vb = __builtin_nontemporal_load(&val4[lane + 64]);
    }

    // stage 2: 8 independent int8 gathers in flight; dequant via LDS scales
    // (bucket 0 quantizes to 0 -> no padding guard needed)
    int   b[8];
    float q[8];
    #pragma unroll
    for (int j = 0; j < 4; ++j) {
        b[j] = ia[j] % NUM_BUCKETS;
        q[j] = (float)table8[b[j]];
    }
    #pragma unroll
    for (int j = 0; j < 4; ++j) {
        b[4 + j] = second ? (ib[j] % NUM_BUCKETS) : 0;
        q[4 + j] = second ? (float)table8[b[4 + j]] : 0.0f;
    }

    // stage 3: acc += q * step[slice] * v
    #pragma unroll
    for (int j = 0; j < 4; ++j)
        atomicAdd(&acc[wave][fa[j] & (NUM_SEGMENTS - 1)],
                  q[j] * sscale[b[j] >> SLICE_LOG2] * va[j]);
    if (second) {
        #pragma unroll
        for (int j = 0; j < 4; ++j)
            atomicAdd(&acc[wave][fb[j] & (NUM_SEGMENTS - 1)],
                      q[4 + j] * sscale[b[4 + j] >> SLICE_LOG2] * vb[j]);
    }

    __syncthreads();

    if (lane >= 1)
        __builtin_nontemporal_store(acc[wave][lane],
                                    &out[row * NUM_FIELDS + (lane - 1)]);
}

// ---- fallback: fp32 table direct (only if d_ws can't hold table + scales)
#define BLOCK_F   256
#define ROWS_F    4
__global__ __launch_bounds__(BLOCK_F, 8) void wide_pool_f32(
    const int*   __restrict__ indexes,
    const int*   __restrict__ fields,
    const float* __restrict__ values,
    const float* __restrict__ table,
    float*       __restrict__ out)
{
    __shared__ float acc[ROWS_F][NUM_SEGMENTS];
    const int tid  = threadIdx.x;
    const int wave = tid >> 6;
    const int lane = tid & 63;
    acc[wave][lane] = 0.0f;
    __syncthreads();
    const long row  = (long)blockIdx.x * ROWS_F + wave;
    const long base = row * SEQ;
    const int4v*   idx4 = (const int4v*)  (indexes + base);
    const int4v*   fld4 = (const int4v*)  (fields  + base);
    const float4v* val4 = (const float4v*)(values  + base);
    const bool second = (lane < 125 - 64);
    int4v   ia = __builtin_nontemporal_load(&idx4[lane]);
    int4v   fa = __builtin_nontemporal_load(&fld4[lane]);
    float4v va = __builtin_nontemporal_load(&val4[lane]);
    int4v   ib = {0,0,0,0}; int4v fb = {0,0,0,0}; float4v vb = {0.f,0.f,0.f,0.f};
    if (second) {
        ib = __builtin_nontemporal_load(&idx4[lane + 64]);
        fb = __builtin_nontemporal_load(&fld4[lane + 64]);
        vb = __builtin_nontemporal_load(&val4[lane + 64]);
    }
    float e[8];
    #pragma unroll
    for (int j = 0; j < 4; ++j) e[j] = table[ia[j] % NUM_BUCKETS];
    #pragma unroll
    for (int j = 0; j < 4; ++j) e[4 + j] = second ? table[ib[j] % NUM_BUCKETS] : 0.0f;
    #pragma unroll
    for (int j = 0; j < 4; ++j)
        atomicAdd(&acc[wave][fa[j] & (NUM_SEGMENTS - 1)], e[j] * va[j]);
    if (second) {
        #pragma unroll
        for (int j = 0; j < 4; ++j)
            atomicAdd(&acc[wave][fb[j] & (NUM_SEGMENTS - 1)], e[4 + j] * vb[j]);
    }
    __syncthreads();
    if (lane >= 1) out[row * NUM_FIELDS + (lane - 1)] = acc[wave][lane];
}

extern "C" void kernel_launch(void* const* d_in, const int* in_sizes, int n_in,
                              void* d_out, int out_size, void* d_ws, size_t ws_size,
                              hipStream_t stream) {
    const int*   indexes = (const int*)  d_in[0];
    const int*   fields  = (const int*)  d_in[1];
    const float* values  = (const float*)d_in[2];
    const float* table   = (const float*)d_in[3];
    float*       out     = (float*)      d_out;

    const size_t need = (size_t)NUM_BUCKETS + 4 * (size_t)N_SLICES;  // 4 MB + 3.9 KB
    if (ws_size >= need) {
        schar* t8  = (schar*)d_ws;
        float* scl = (float*)((char*)d_ws + SCALES_OFF);
        quant_slice<<<N_SLICES, BLOCK_Q, 0, stream>>>(
            (const float4v*)table, (char4v*)t8, scl);
        wide_pool_i8<<<BATCH / ROWS_PER_BLK, BLOCK_MAIN, 0, stream>>>(
            indexes, fields, values, t8, scl, out);
    } else {
        wide_pool_f32<<<BATCH / ROWS_F, BLOCK_F, 0, stream>>>(
            indexes, fields, values, table, out);
    }
}